// Round 7
// baseline (1330.783 us; speedup 1.0000x reference)
//
#include <hip/hip_runtime.h>
#include <hip/hip_bf16.h>
#include <cstdint>
#include <cstddef>

// Problem constants (NeuTraLAD): B=8192, D=512, H=1024, K=11 views.
#define NB 8192
#define ND 512
#define NH 1024
#define NK 11

typedef __bf16 bf16x8 __attribute__((ext_vector_type(8)));
typedef float f32x4 __attribute__((ext_vector_type(4)));

// ---------------------------------------------------------------------------
// Convert f32 -> bf16 elementwise
// ---------------------------------------------------------------------------
__global__ void cvt_f32_bf16(const float* __restrict__ in,
                             __hip_bfloat16* __restrict__ out, int n) {
  int i = blockIdx.x * blockDim.x + threadIdx.x;
  if (i < n) out[i] = __float2bfloat16(in[i]);
}

// ---------------------------------------------------------------------------
// Transpose f32 [R,C] -> bf16 [C,R], batched over blockIdx.z (stride R*C)
// ---------------------------------------------------------------------------
__global__ void transpose_f32_bf16(const float* __restrict__ in,
                                   __hip_bfloat16* __restrict__ out,
                                   int R, int C) {
  __shared__ float tile[32][33];
  const float* inb = in + (size_t)blockIdx.z * R * C;
  __hip_bfloat16* outb = out + (size_t)blockIdx.z * R * C;
  int cx = blockIdx.x * 32 + threadIdx.x;  // input col
  int ry = blockIdx.y * 32;                // input row base
  for (int j = threadIdx.y; j < 32; j += 8)
    tile[j][threadIdx.x] = inb[(size_t)(ry + j) * C + cx];
  __syncthreads();
  int ox = ry + threadIdx.x;  // output col = input row
  int oy = blockIdx.x * 32;   // output row base = input col base
  for (int j = threadIdx.y; j < 32; j += 8)
    outb[(size_t)(oy + j) * R + ox] = __float2bfloat16(tile[threadIdx.x][j]);
}

__device__ __forceinline__ float fast_tanh(float x) {
  float e = __expf(2.0f * x);
  return 1.0f - 2.0f / (e + 1.0f);
}

// ---------------------------------------------------------------------------
// MFMA GEMM (NT): C[M,N] = act(A[M,Kd] * Bt[N,Kd]^T + bias[N])
// 128x128 block tile, 256 threads = 4 waves (2x2), wave = 4x4 tiles of
// mfma_f32_16x16x32_bf16.
// R7 restructure (R4-R6 showed per-barrier vmcnt(0) drain dominates):
//  - B (weights, <=2 MB/slice, L2-hot) loaded DIRECT global->VGPR; only A
//    staged via global_load_lds. Halves staged bytes per barrier.
//  - A LDS double-buffered (2 x 16 KB, BK=64), k-loop unrolled 2x so buffer
//    indices are compile-time -> ONE barrier per 64-k half; staging of the
//    next half overlaps the current half's ds_read+MFMA. Safe: compiler
//    emits lgkmcnt(0) before s_barrier, so ds_reads drain before the
//    opposite buffer is overwritten.
// Verified keepers: grid x = row panel (XCD affinity, R4: FETCH 198->41MB);
// 3-bit XOR chunk swizzle (R5/R6: SQ_LDS_BANK_CONFLICT == 0); swapped MFMA
// operands -> lane holds 4 consecutive cols -> 8 B packed stores.
// Kd must be a multiple of 128 (512 and 1024 here).
// EPI: 1 = tanh->bf16, 2 = relu->bf16, 3 = plain->bf16
// ---------------------------------------------------------------------------
template <int EPI>
__global__ __launch_bounds__(256) void gemm_bt(
    const __hip_bfloat16* __restrict__ A, long sAz, int lda,
    const __hip_bfloat16* __restrict__ Bt, long sBz, int ldb,
    const float* __restrict__ bias, long sBiasZ,
    __hip_bfloat16* __restrict__ C, long sCz, int ldc, int Kd) {
  __shared__ __align__(16) __hip_bfloat16 As[2][128 * 64];

  const int z = blockIdx.z;
  const __hip_bfloat16* Ab = A + (size_t)z * sAz;
  const __hip_bfloat16* Bb = Bt + (size_t)z * sBz;
  const float* biasb = bias + (size_t)z * sBiasZ;
  __hip_bfloat16* Cb = C + (size_t)z * sCz;

  const int bm = blockIdx.x, bn = blockIdx.y;  // x = row panel (XCD affinity)
  const int t = threadIdx.x;
  const int lane = t & 63, w = t >> 6;
  const int wm = w >> 1, wn = w & 1;
  const int r = lane & 15, q = lane >> 4;

  f32x4 acc[4][4] = {};
  bf16x8 Bf[2][2][4];  // [buf][ks][nt]

  // A staging: 1024 chunks of 16 B, 4 per thread. Chunk c -> row c>>3;
  // LDS slot c&7 holds global chunk (c&7)^(row&7) (XOR self-inverse).
  int rowS[4], gofs[4];
#pragma unroll
  for (int m = 0; m < 4; ++m) {
    int c = t + m * 256;
    rowS[m] = c >> 3;
    gofs[m] = ((c & 7) ^ (rowS[m] & 7)) * 8;
  }
  const size_t rowA = (size_t)bm * 128, rowB = (size_t)bn * 128;
  // Per-lane B pointer: row = rowB + wn*64 + nt*16 + r, elems kb + ks*32 + q*8
  const __hip_bfloat16* bptr = Bb + (rowB + wn * 64 + r) * (size_t)ldb + q * 8;

#define STAGE_A(kb, pb)                                                        \
  {                                                                            \
    _Pragma("unroll") for (int m = 0; m < 4; ++m) {                            \
      int c = t + m * 256;                                                     \
      __builtin_amdgcn_global_load_lds(                                        \
          (const __attribute__((address_space(1))) void*)(                     \
              Ab + (rowA + rowS[m]) * lda + (kb) + gofs[m]),                   \
          (__attribute__((address_space(3))) void*)(&As[pb][c * 8]), 16, 0,    \
          0);                                                                  \
    }                                                                          \
  }

#define LOAD_B(ib, kb)                                                         \
  {                                                                            \
    _Pragma("unroll") for (int ks = 0; ks < 2; ++ks)                           \
        _Pragma("unroll") for (int nt = 0; nt < 4; ++nt)                       \
            Bf[ib][ks][nt] = *(const bf16x8*)(bptr + (size_t)nt * 16 * ldb +   \
                                              (kb) + ks * 32);                 \
  }

#define COMPUTE_HALF(ib, pb)                                                   \
  {                                                                            \
    _Pragma("unroll") for (int ks = 0; ks < 2; ++ks) {                         \
      bf16x8 af[4];                                                            \
      _Pragma("unroll") for (int mt = 0; mt < 4; ++mt) {                       \
        int tr = wm * 64 + mt * 16 + r;                                        \
        int sl = (ks * 4 + q) ^ (tr & 7);                                      \
        af[mt] = *(const bf16x8*)&As[pb][tr * 64 + sl * 8];                    \
      }                                                                        \
      _Pragma("unroll") for (int mt = 0; mt < 4; ++mt)                         \
          _Pragma("unroll") for (int nt = 0; nt < 4; ++nt)                     \
              acc[mt][nt] = __builtin_amdgcn_mfma_f32_16x16x32_bf16(           \
                  Bf[ib][ks][nt], af[mt], acc[mt][nt], 0, 0, 0);               \
    }                                                                          \
  }

  STAGE_A(0, 0);
  LOAD_B(0, 0);
  __syncthreads();
  for (int k0 = 0; k0 < Kd; k0 += 128) {
    if (k0 + 64 < Kd) {
      STAGE_A(k0 + 64, 1);
      LOAD_B(1, k0 + 64);
    }
    COMPUTE_HALF(0, 0);
    __syncthreads();
    if (k0 + 128 < Kd) {
      STAGE_A(k0 + 128, 0);
      LOAD_B(0, k0 + 128);
    }
    COMPUTE_HALF(1, 1);
    __syncthreads();
  }
#undef STAGE_A
#undef LOAD_B
#undef COMPUTE_HALF

  // Epilogue (operand-swapped layout): lane holds M-row = mt*16 + r (fixed),
  // N-cols = nt*16 + q*4 + j (4 consecutive) -> 8 B packed stores.
  const int colg0 = bn * 128 + wn * 64;
  const int rowg0 = bm * 128 + wm * 64;
#pragma unroll
  for (int mt = 0; mt < 4; ++mt) {
    int row = rowg0 + mt * 16 + r;
#pragma unroll
    for (int nt = 0; nt < 4; ++nt) {
      int col = colg0 + nt * 16 + q * 4;
      const f32x4 bv = *(const f32x4*)&biasb[col];
      union {
        __hip_bfloat16 h[4];
        uint2 u;
      } pk;
#pragma unroll
      for (int j = 0; j < 4; ++j) {
        float v = acc[mt][nt][j] + bv[j];
        if (EPI == 1) v = fast_tanh(v);
        if (EPI == 2) v = fmaxf(v, 0.0f);
        pk.h[j] = __float2bfloat16(v);
      }
      *(uint2*)&Cb[(size_t)row * ldc + col] = pk.u;
    }
  }
}

// ---------------------------------------------------------------------------
// Final: one WAVE per batch row b. Gram G = Z Z^T (Z: 12 x NH, padded to 16)
// via mfma(a, a, acc) — NT A/B fragment layouts are identical.
// zc layout: [12, Bc, NH] bf16.
// ---------------------------------------------------------------------------
__global__ __launch_bounds__(256) void final_gram(
    const __hip_bfloat16* __restrict__ zc, float* __restrict__ out, int Bc) {
  __shared__ float Gs[4][16][16];
  const int t = threadIdx.x;
  const int w = t >> 6, lane = t & 63;
  const int b = blockIdx.x * 4 + w;
  const int r = lane & 15;   // slice index
  const int q = lane >> 4;   // k-quad

  const int rs = r < 12 ? r : 11;
  const __hip_bfloat16* base = zc + ((size_t)rs * Bc + b) * NH + q * 8;

  f32x4 acc = {};
#pragma unroll
  for (int k0 = 0; k0 < NH; k0 += 32) {
    bf16x8 a = {};
    if (r < 12) a = *(const bf16x8*)(base + k0);
    acc = __builtin_amdgcn_mfma_f32_16x16x32_bf16(a, a, acc, 0, 0, 0);
  }

#pragma unroll
  for (int j = 0; j < 4; ++j) Gs[w][q * 4 + j][r] = acc[j];
  __syncthreads();

  float term = 0.0f;
  if (lane >= 1 && lane < 12) {
    float nrm[12];
#pragma unroll
    for (int i = 0; i < 12; ++i)
      nrm[i] = fmaxf(sqrtf(Gs[w][i][i]), 1e-8f);
    const int k = lane;
    float pos = __expf(Gs[w][0][k] / (nrm[0] * nrm[k]));
    float neg = 0.0f;
#pragma unroll
    for (int l = 1; l < 12; ++l)
      if (l != k) neg += __expf(Gs[w][k][l] / (nrm[k] * nrm[l]));
    term = __logf(pos / (pos + neg));
  }
#pragma unroll
  for (int m = 1; m < 16; m <<= 1) term += __shfl_xor(term, m);
  if (lane == 0) out[b] = -term;
}

// ---------------------------------------------------------------------------
extern "C" void kernel_launch(void* const* d_in, const int* in_sizes, int n_in,
                              void* d_out, int out_size, void* d_ws,
                              size_t ws_size, hipStream_t stream) {
  const float* x = (const float*)d_in[0];    // [B,D]
  const float* Wt1 = (const float*)d_in[1];  // [K,D,H]
  const float* bt1 = (const float*)d_in[2];  // [K,H]
  const float* Wt2 = (const float*)d_in[3];  // [K,H,D]
  const float* bt2 = (const float*)d_in[4];  // [K,D]
  const float* We1 = (const float*)d_in[5];  // [D,H]
  const float* be1 = (const float*)d_in[6];  // [H]
  const float* We2 = (const float*)d_in[7];  // [H,H]
  const float* be2 = (const float*)d_in[8];  // [H]
  float* out = (float*)d_out;                // [B]

  char* ws = (char*)d_ws;
  size_t off = 0;
  auto alloc = [&](size_t bytes) {
    void* p = ws + off;
    off += (bytes + 255) & ~(size_t)255;
    return p;
  };

  // Persistent bf16 weight transposes (~26 MB)
  __hip_bfloat16* Wt1t = (__hip_bfloat16*)alloc((size_t)NK * NH * ND * 2);  // [K,H,D]
  __hip_bfloat16* Wt2t = (__hip_bfloat16*)alloc((size_t)NK * ND * NH * 2);  // [K,D,H]
  __hip_bfloat16* We1t = (__hip_bfloat16*)alloc((size_t)NH * ND * 2);       // [H,D]
  __hip_bfloat16* We2t = (__hip_bfloat16*)alloc((size_t)NH * NH * 2);       // [H,H]
  const size_t wbytes = off;

  // Pick largest batch chunk Bc. Buffer plan (zc ALIASES txc's region —
  // txc is dead after G3, G4 only reads h1):
  //   region0 = max(txc, zc) = 12*Bc*NH*2 ;  h1 = 12*Bc*NH*2
  int Bc = NB;
  while (Bc > 128) {
    size_t need = wbytes + 2 * ((size_t)12 * Bc * NH * 2) + 4096;
    if (need <= ws_size) break;
    Bc >>= 1;
  }
  __hip_bfloat16* region0 = (__hip_bfloat16*)alloc((size_t)12 * Bc * NH * 2);
  __hip_bfloat16* h1 = (__hip_bfloat16*)alloc((size_t)12 * Bc * NH * 2);
  __hip_bfloat16* txc = region0;  // [12, Bc, ND] during G1..G3
  __hip_bfloat16* zc = region0;   // [12, Bc, NH] during G4..final

  // One-time weight transposes to bf16 [N][K] layout
  transpose_f32_bf16<<<dim3(NH / 32, ND / 32, NK), dim3(32, 8), 0, stream>>>(
      Wt1, Wt1t, ND, NH);
  transpose_f32_bf16<<<dim3(ND / 32, NH / 32, NK), dim3(32, 8), 0, stream>>>(
      Wt2, Wt2t, NH, ND);
  transpose_f32_bf16<<<dim3(NH / 32, ND / 32, 1), dim3(32, 8), 0, stream>>>(
      We1, We1t, ND, NH);
  transpose_f32_bf16<<<dim3(NH / 32, NH / 32, 1), dim3(32, 8), 0, stream>>>(
      We2, We2t, NH, NH);

  for (int cs = 0; cs < NB; cs += Bc) {
    // 1) x chunk -> bf16 (slice 0 of txc)
    cvt_f32_bf16<<<(Bc * ND) / 256, 256, 0, stream>>>(
        x + (size_t)cs * ND, txc, Bc * ND);
    // 2) G1: hx_k = tanh(x @ Wt1[k] + bt1) -> h1 slices 0..10  (Kd=512)
    gemm_bt<1><<<dim3(Bc / 128, NH / 128, NK), 256, 0, stream>>>(
        txc, 0L, ND, Wt1t, (long)NH * ND, ND, bt1, (long)NH, h1,
        (long)Bc * NH, NH, ND);
    // 3) G2: tx_k = hx_k @ Wt2[k] + bt2 -> txc slices 1..11    (Kd=1024)
    gemm_bt<3><<<dim3(Bc / 128, ND / 128, NK), 256, 0, stream>>>(
        h1, (long)Bc * NH, NH, Wt2t, (long)ND * NH, NH, bt2, (long)ND,
        txc + (size_t)Bc * ND, (long)Bc * ND, ND, NH);
    // 4) G3: e1_s = relu(tx_s @ We1 + be1) -> h1 slices 0..11  (Kd=512)
    gemm_bt<2><<<dim3(Bc / 128, NH / 128, 12), 256, 0, stream>>>(
        txc, (long)Bc * ND, ND, We1t, 0L, ND, be1, 0L, h1, (long)Bc * NH,
        NH, ND);
    // 5) G4: z_s = e1_s @ We2 + be2 -> zc slices 0..11         (Kd=1024)
    gemm_bt<3><<<dim3(Bc / 128, NH / 128, 12), 256, 0, stream>>>(
        h1, (long)Bc * NH, NH, We2t, 0L, NH, be2, 0L, zc, (long)Bc * NH,
        NH, NH);
    // 6) final score for this chunk: one wave per batch row
    final_gram<<<Bc / 4, 256, 0, stream>>>(zc, out + cs, Bc);
  }
}

// Round 8
// 973.381 us; speedup vs baseline: 1.3672x; 1.3672x over previous
//
#include <hip/hip_runtime.h>
#include <hip/hip_bf16.h>
#include <cstdint>
#include <cstddef>

// Problem constants (NeuTraLAD): B=8192, D=512, H=1024, K=11 views.
#define NB 8192
#define ND 512
#define NH 1024
#define NK 11

typedef __bf16 bf16x8 __attribute__((ext_vector_type(8)));
typedef float f32x4 __attribute__((ext_vector_type(4)));

// ---------------------------------------------------------------------------
// Convert f32 -> bf16 elementwise
// ---------------------------------------------------------------------------
__global__ void cvt_f32_bf16(const float* __restrict__ in,
                             __hip_bfloat16* __restrict__ out, int n) {
  int i = blockIdx.x * blockDim.x + threadIdx.x;
  if (i < n) out[i] = __float2bfloat16(in[i]);
}

// ---------------------------------------------------------------------------
// Transpose f32 [R,C] -> bf16 [C,R], batched over blockIdx.z (stride R*C)
// ---------------------------------------------------------------------------
__global__ void transpose_f32_bf16(const float* __restrict__ in,
                                   __hip_bfloat16* __restrict__ out,
                                   int R, int C) {
  __shared__ float tile[32][33];
  const float* inb = in + (size_t)blockIdx.z * R * C;
  __hip_bfloat16* outb = out + (size_t)blockIdx.z * R * C;
  int cx = blockIdx.x * 32 + threadIdx.x;  // input col
  int ry = blockIdx.y * 32;                // input row base
  for (int j = threadIdx.y; j < 32; j += 8)
    tile[j][threadIdx.x] = inb[(size_t)(ry + j) * C + cx];
  __syncthreads();
  int ox = ry + threadIdx.x;  // output col = input row
  int oy = blockIdx.x * 32;   // output row base = input col base
  for (int j = threadIdx.y; j < 32; j += 8)
    outb[(size_t)(oy + j) * R + ox] = __float2bfloat16(tile[threadIdx.x][j]);
}

__device__ __forceinline__ float fast_tanh(float x) {
  float e = __expf(2.0f * x);
  return 1.0f - 2.0f / (e + 1.0f);
}

// ---------------------------------------------------------------------------
// MFMA GEMM (NT): C[M,N] = act(A[M,Kd] * Bt[N,Kd]^T + bias[N])
// [R6-verified structure — R7's single-barrier/direct-B variant regressed
// 37% (VALUBusy 32->10.5): direct B VGPR loads + in-order vmcnt serialized
// the pipeline. Do not re-attempt source-level pipelining here.]
// 128x128 block tile, 256 threads = 4 waves (2x2), wave = 4x4 tiles of
// mfma_f32_16x16x32_bf16; global_load_lds width-16 staging of BOTH A and B.
// BK per shape [R4/R5 measured]: Kd=512 -> BK=32 (16 KB LDS), Kd=1024 ->
// BK=64 (G4 79->74 us). Grid x = row panel (XCD affinity: FETCH 198->41MB).
// XOR chunk swizzles (both measured conflict-free). MFMA operands swapped
// -> lane holds 4 consecutive cols -> 8 B packed stores.
// EPI: 1 = tanh->bf16, 2 = relu->bf16, 3 = plain->bf16
// ---------------------------------------------------------------------------
template <int EPI, int BK>
__global__ __launch_bounds__(256) void gemm_bt(
    const __hip_bfloat16* __restrict__ A, long sAz, int lda,
    const __hip_bfloat16* __restrict__ Bt, long sBz, int ldb,
    const float* __restrict__ bias, long sBiasZ,
    __hip_bfloat16* __restrict__ C, long sCz, int ldc, int Kd) {
  __shared__ __align__(16) __hip_bfloat16 As[128 * BK];
  __shared__ __align__(16) __hip_bfloat16 Bs[128 * BK];

  const int z = blockIdx.z;
  const __hip_bfloat16* Ab = A + (size_t)z * sAz;
  const __hip_bfloat16* Bb = Bt + (size_t)z * sBz;
  const float* biasb = bias + (size_t)z * sBiasZ;
  __hip_bfloat16* Cb = C + (size_t)z * sCz;

  const int bm = blockIdx.x, bn = blockIdx.y;  // x = row panel (XCD affinity)
  const int t = threadIdx.x;
  const int lane = t & 63, w = t >> 6;
  const int wm = w >> 1, wn = w & 1;
  const int r = lane & 15, q = lane >> 4;

  f32x4 acc[4][4] = {};

  constexpr int CPT = (128 * BK / 8) / 256;
  int rowS[CPT], gofs[CPT];
#pragma unroll
  for (int m = 0; m < CPT; ++m) {
    int c = t + m * 256;
    if constexpr (BK == 32) {
      rowS[m] = c >> 2;
      gofs[m] = (((c & 3) ^ ((rowS[m] >> 1) & 3)) * 8);
    } else {
      rowS[m] = c >> 3;
      gofs[m] = (((c & 7) ^ (rowS[m] & 7)) * 8);
    }
  }
  const size_t rowA = (size_t)bm * 128, rowB = (size_t)bn * 128;

  for (int k0 = 0; k0 < Kd; k0 += BK) {
#pragma unroll
    for (int m = 0; m < CPT; ++m) {
      int c = t + m * 256;
      __builtin_amdgcn_global_load_lds(
          (const __attribute__((address_space(1))) void*)(Ab + (rowA + rowS[m]) * lda + k0 + gofs[m]),
          (__attribute__((address_space(3))) void*)(As + c * 8), 16, 0, 0);
      __builtin_amdgcn_global_load_lds(
          (const __attribute__((address_space(1))) void*)(Bb + (rowB + rowS[m]) * ldb + k0 + gofs[m]),
          (__attribute__((address_space(3))) void*)(Bs + c * 8), 16, 0, 0);
    }
    __syncthreads();

#pragma unroll
    for (int ks = 0; ks < BK / 32; ++ks) {
      bf16x8 af[4], bfr[4];
#pragma unroll
      for (int mt = 0; mt < 4; ++mt) {
        int tr = wm * 64 + mt * 16 + r;
        int sl;
        if constexpr (BK == 32) sl = q ^ ((tr >> 1) & 3);
        else sl = (ks * 4 + q) ^ (tr & 7);
        af[mt] = *(const bf16x8*)&As[tr * BK + sl * 8];
      }
#pragma unroll
      for (int nt = 0; nt < 4; ++nt) {
        int tr = wn * 64 + nt * 16 + r;
        int sl;
        if constexpr (BK == 32) sl = q ^ ((tr >> 1) & 3);
        else sl = (ks * 4 + q) ^ (tr & 7);
        bfr[nt] = *(const bf16x8*)&Bs[tr * BK + sl * 8];
      }
#pragma unroll
      for (int mt = 0; mt < 4; ++mt)
#pragma unroll
        for (int nt = 0; nt < 4; ++nt)
          acc[mt][nt] = __builtin_amdgcn_mfma_f32_16x16x32_bf16(
              bfr[nt], af[mt], acc[mt][nt], 0, 0, 0);
    }
    __syncthreads();
  }

  // Epilogue (operand-swapped layout): lane holds M-row = mt*16 + r (fixed),
  // N-cols = nt*16 + q*4 + j (4 consecutive) -> 8 B packed stores.
  const int colg0 = bn * 128 + wn * 64;
  const int rowg0 = bm * 128 + wm * 64;
#pragma unroll
  for (int mt = 0; mt < 4; ++mt) {
    int row = rowg0 + mt * 16 + r;
#pragma unroll
    for (int nt = 0; nt < 4; ++nt) {
      int col = colg0 + nt * 16 + q * 4;
      const f32x4 bv = *(const f32x4*)&biasb[col];
      union {
        __hip_bfloat16 h[4];
        uint2 u;
      } pk;
#pragma unroll
      for (int j = 0; j < 4; ++j) {
        float v = acc[mt][nt][j] + bv[j];
        if (EPI == 1) v = fast_tanh(v);
        if (EPI == 2) v = fmaxf(v, 0.0f);
        pk.h[j] = __float2bfloat16(v);
      }
      *(uint2*)&Cb[(size_t)row * ldc + col] = pk.u;
    }
  }
}

// ---------------------------------------------------------------------------
// Final v3: zc relaid as [Bc][12][NH] (G4 writes it that way via ldc=12*NH)
// -> per-b working set is one contiguous 24 KB window. TWO waves per b
// (each does half of H; partial Grams summed from LDS) -> serial MFMA
// chain halved. Block = 256 thr = 4 waves = 2 b's.
// ---------------------------------------------------------------------------
__global__ __launch_bounds__(256) void final_gram(
    const __hip_bfloat16* __restrict__ zc, float* __restrict__ out, int Bc) {
  __shared__ float Gs[2][2][16][16];
  const int t = threadIdx.x;
  const int w = t >> 6, lane = t & 63;
  const int bi = w >> 1;  // which b of the pair
  const int hh = w & 1;   // which H-half
  const int b = blockIdx.x * 2 + bi;
  const int r = lane & 15;  // slice index
  const int q = lane >> 4;  // k-quad

  const int rs = r < 12 ? r : 11;
  const __hip_bfloat16* base =
      zc + ((size_t)b * 12 + rs) * NH + hh * (NH / 2) + q * 8;

  f32x4 acc = {};
#pragma unroll
  for (int k0 = 0; k0 < NH / 2; k0 += 32) {
    bf16x8 a = {};
    if (r < 12) a = *(const bf16x8*)(base + k0);
    acc = __builtin_amdgcn_mfma_f32_16x16x32_bf16(a, a, acc, 0, 0, 0);
  }

  // C/D layout: col = r, row = q*4 + j
#pragma unroll
  for (int j = 0; j < 4; ++j) Gs[bi][hh][q * 4 + j][r] = acc[j];
  __syncthreads();

  if (hh == 0) {
    float term = 0.0f;
    if (lane >= 1 && lane < 12) {
      const float(*G0)[16] = Gs[bi][0];
      const float(*G1)[16] = Gs[bi][1];
      float nrm[12];
#pragma unroll
      for (int i = 0; i < 12; ++i)
        nrm[i] = fmaxf(sqrtf(G0[i][i] + G1[i][i]), 1e-8f);
      const int k = lane;
      float pos = __expf((G0[0][k] + G1[0][k]) / (nrm[0] * nrm[k]));
      float neg = 0.0f;
#pragma unroll
      for (int l = 1; l < 12; ++l)
        if (l != k) neg += __expf((G0[k][l] + G1[k][l]) / (nrm[k] * nrm[l]));
      term = __logf(pos / (pos + neg));
    }
#pragma unroll
    for (int m = 1; m < 16; m <<= 1) term += __shfl_xor(term, m);
    if (lane == 0) out[b] = -term;
  }
}

// ---------------------------------------------------------------------------
extern "C" void kernel_launch(void* const* d_in, const int* in_sizes, int n_in,
                              void* d_out, int out_size, void* d_ws,
                              size_t ws_size, hipStream_t stream) {
  const float* x = (const float*)d_in[0];    // [B,D]
  const float* Wt1 = (const float*)d_in[1];  // [K,D,H]
  const float* bt1 = (const float*)d_in[2];  // [K,H]
  const float* Wt2 = (const float*)d_in[3];  // [K,H,D]
  const float* bt2 = (const float*)d_in[4];  // [K,D]
  const float* We1 = (const float*)d_in[5];  // [D,H]
  const float* be1 = (const float*)d_in[6];  // [H]
  const float* We2 = (const float*)d_in[7];  // [H,H]
  const float* be2 = (const float*)d_in[8];  // [H]
  float* out = (float*)d_out;                // [B]

  char* ws = (char*)d_ws;
  size_t off = 0;
  auto alloc = [&](size_t bytes) {
    void* p = ws + off;
    off += (bytes + 255) & ~(size_t)255;
    return p;
  };

  // Persistent bf16 weight transposes (~26 MB)
  __hip_bfloat16* Wt1t = (__hip_bfloat16*)alloc((size_t)NK * NH * ND * 2);  // [K,H,D]
  __hip_bfloat16* Wt2t = (__hip_bfloat16*)alloc((size_t)NK * ND * NH * 2);  // [K,D,H]
  __hip_bfloat16* We1t = (__hip_bfloat16*)alloc((size_t)NH * ND * 2);       // [H,D]
  __hip_bfloat16* We2t = (__hip_bfloat16*)alloc((size_t)NH * NH * 2);       // [H,H]
  const size_t wbytes = off;

  // Pick largest batch chunk Bc. zc ALIASES txc's region (txc dead after G3).
  int Bc = NB;
  while (Bc > 128) {
    size_t need = wbytes + 2 * ((size_t)12 * Bc * NH * 2) + 4096;
    if (need <= ws_size) break;
    Bc >>= 1;
  }
  __hip_bfloat16* region0 = (__hip_bfloat16*)alloc((size_t)12 * Bc * NH * 2);
  __hip_bfloat16* h1 = (__hip_bfloat16*)alloc((size_t)12 * Bc * NH * 2);
  __hip_bfloat16* txc = region0;  // [12, Bc, ND] during G1..G3
  __hip_bfloat16* zc = region0;   // [Bc, 12, NH] during G4..final

  // One-time weight transposes to bf16 [N][K] layout
  transpose_f32_bf16<<<dim3(NH / 32, ND / 32, NK), dim3(32, 8), 0, stream>>>(
      Wt1, Wt1t, ND, NH);
  transpose_f32_bf16<<<dim3(ND / 32, NH / 32, NK), dim3(32, 8), 0, stream>>>(
      Wt2, Wt2t, NH, ND);
  transpose_f32_bf16<<<dim3(NH / 32, ND / 32, 1), dim3(32, 8), 0, stream>>>(
      We1, We1t, ND, NH);
  transpose_f32_bf16<<<dim3(NH / 32, NH / 32, 1), dim3(32, 8), 0, stream>>>(
      We2, We2t, NH, NH);

  for (int cs = 0; cs < NB; cs += Bc) {
    // 1) x chunk -> bf16 (slice 0 of txc)
    cvt_f32_bf16<<<(Bc * ND) / 256, 256, 0, stream>>>(
        x + (size_t)cs * ND, txc, Bc * ND);
    // 2) G1: hx_k = tanh(x @ Wt1[k] + bt1) -> h1 slices 0..10  (Kd=512: BK32)
    gemm_bt<1, 32><<<dim3(Bc / 128, NH / 128, NK), 256, 0, stream>>>(
        txc, 0L, ND, Wt1t, (long)NH * ND, ND, bt1, (long)NH, h1,
        (long)Bc * NH, NH, ND);
    // 3) G2: tx_k = hx_k @ Wt2[k] + bt2 -> txc slices 1..11    (Kd=1024: BK64)
    gemm_bt<3, 64><<<dim3(Bc / 128, ND / 128, NK), 256, 0, stream>>>(
        h1, (long)Bc * NH, NH, Wt2t, (long)ND * NH, NH, bt2, (long)ND,
        txc + (size_t)Bc * ND, (long)Bc * ND, ND, NH);
    // 4) G3: e1_s = relu(tx_s @ We1 + be1) -> h1 slices 0..11  (Kd=512: BK32)
    gemm_bt<2, 32><<<dim3(Bc / 128, NH / 128, 12), 256, 0, stream>>>(
        txc, (long)Bc * ND, ND, We1t, 0L, ND, be1, 0L, h1, (long)Bc * NH,
        NH, ND);
    // 5) G4: z_s -> zc in [b][slice][h] layout: sCz=NH, ldc=12*NH (Kd=1024)
    gemm_bt<3, 64><<<dim3(Bc / 128, NH / 128, 12), 256, 0, stream>>>(
        h1, (long)Bc * NH, NH, We2t, 0L, NH, be2, 0L, zc, (long)NH,
        12 * NH, NH);
    // 6) final score: 2 waves per b, 2 b's per block
    final_gram<<<Bc / 2, 256, 0, stream>>>(zc, out + cs, Bc);
  }
}

// Round 9
// 870.873 us; speedup vs baseline: 1.5281x; 1.1177x over previous
//
#include <hip/hip_runtime.h>
#include <hip/hip_bf16.h>
#include <cstdint>
#include <cstddef>

// Problem constants (NeuTraLAD): B=8192, D=512, H=1024, K=11 views.
#define NB 8192
#define ND 512
#define NH 1024
#define NK 11

typedef __bf16 bf16x8 __attribute__((ext_vector_type(8)));
typedef float f32x4 __attribute__((ext_vector_type(4)));

// ---------------------------------------------------------------------------
// Convert f32 -> bf16 elementwise
// ---------------------------------------------------------------------------
__global__ void cvt_f32_bf16(const float* __restrict__ in,
                             __hip_bfloat16* __restrict__ out, int n) {
  int i = blockIdx.x * blockDim.x + threadIdx.x;
  if (i < n) out[i] = __float2bfloat16(in[i]);
}

// ---------------------------------------------------------------------------
// ONE preamble launch: all four weight transposes f32 [R,C] -> bf16 [C,R].
// z 0..10 = Wt1 slices, 11..21 = Wt2 slices, 22 = We1, 23 = We2.
// Grid sized for the largest shape; out-of-range tiles early-out (uniform).
// ---------------------------------------------------------------------------
__global__ void transpose_all(const float* __restrict__ Wt1,
                              const float* __restrict__ Wt2,
                              const float* __restrict__ We1,
                              const float* __restrict__ We2,
                              __hip_bfloat16* __restrict__ Wt1t,
                              __hip_bfloat16* __restrict__ Wt2t,
                              __hip_bfloat16* __restrict__ We1t,
                              __hip_bfloat16* __restrict__ We2t) {
  __shared__ float tile[32][33];
  const int z = blockIdx.z;
  int R, C;
  const float* inb;
  __hip_bfloat16* outb;
  if (z < NK) {
    R = ND; C = NH;
    inb = Wt1 + (size_t)z * ND * NH;
    outb = Wt1t + (size_t)z * ND * NH;
  } else if (z < 2 * NK) {
    R = NH; C = ND;
    inb = Wt2 + (size_t)(z - NK) * NH * ND;
    outb = Wt2t + (size_t)(z - NK) * NH * ND;
  } else if (z == 2 * NK) {
    R = ND; C = NH;
    inb = We1; outb = We1t;
  } else {
    R = NH; C = NH;
    inb = We2; outb = We2t;
  }
  int cx = blockIdx.x * 32 + threadIdx.x;
  int ry = blockIdx.y * 32;
  if (blockIdx.x * 32 >= C || ry >= R) return;  // uniform early-out
  for (int j = threadIdx.y; j < 32; j += 8)
    tile[j][threadIdx.x] = inb[(size_t)(ry + j) * C + cx];
  __syncthreads();
  int ox = ry + threadIdx.x;
  int oy = blockIdx.x * 32;
  for (int j = threadIdx.y; j < 32; j += 8)
    outb[(size_t)(oy + j) * R + ox] = __float2bfloat16(tile[threadIdx.x][j]);
}

__device__ __forceinline__ float fast_tanh(float x) {
  float e = __expf(2.0f * x);
  return 1.0f - 2.0f / (e + 1.0f);
}

// ---------------------------------------------------------------------------
// MFMA GEMM (NT): C[M,N] = act(A[M,Kd] * Bt[N,Kd]^T + bias[N])
// TM x 128 block tile (TM=128: 256 thr/4 waves; TM=256: 512 thr/8 waves,
// wave grid 4x2 — R9: doubles MFMAs per barrier-pair at 1.5x staged bytes).
// [R7 lesson: do NOT re-attempt direct-B / single-barrier pipelining.]
// BK per shape [R4/R5]: Kd=512 -> BK=32, Kd=1024 -> BK=64.
// Grid x = row panel (XCD affinity: FETCH 198->41MB, R4). XOR chunk
// swizzles (measured conflict-free R5/R6). MFMA operands swapped -> lane
// holds 4 consecutive cols -> 8 B packed stores.
// EPI: 1 = tanh->bf16, 2 = relu->bf16, 3 = plain->bf16
// ---------------------------------------------------------------------------
template <int EPI, int BK, int TM>
__global__ __launch_bounds__(TM * 2) void gemm_bt(
    const __hip_bfloat16* __restrict__ A, long sAz, int lda,
    const __hip_bfloat16* __restrict__ Bt, long sBz, int ldb,
    const float* __restrict__ bias, long sBiasZ,
    __hip_bfloat16* __restrict__ C, long sCz, int ldc, int Kd) {
  __shared__ __align__(16) __hip_bfloat16 As[TM * BK];
  __shared__ __align__(16) __hip_bfloat16 Bs[128 * BK];

  const int z = blockIdx.z;
  const __hip_bfloat16* Ab = A + (size_t)z * sAz;
  const __hip_bfloat16* Bb = Bt + (size_t)z * sBz;
  const float* biasb = bias + (size_t)z * sBiasZ;
  __hip_bfloat16* Cb = C + (size_t)z * sCz;

  const int bm = blockIdx.x, bn = blockIdx.y;  // x = row panel (XCD affinity)
  const int t = threadIdx.x;
  constexpr int T = TM * 2;  // threads
  const int lane = t & 63, w = t >> 6;
  const int wm = w >> 1, wn = w & 1;  // wm 0..TM/64-1, wn 0..1
  const int r = lane & 15, q = lane >> 4;

  f32x4 acc[4][4] = {};

  // Staging chunk->(row, global-offset) with XOR swizzle (self-inverse).
  auto chunk_row = [&](int c) {
    return (BK == 32) ? (c >> 2) : (c >> 3);
  };
  auto chunk_gofs = [&](int c, int row) {
    return (BK == 32) ? ((((c & 3) ^ ((row >> 1) & 3)) * 8))
                      : ((((c & 7) ^ (row & 7)) * 8));
  };
  constexpr int CPTA = BK / 16;          // A chunks per thread
  constexpr int CPTB = 8 * BK / TM;      // B chunks per thread
  const size_t rowA = (size_t)bm * TM, rowB = (size_t)bn * 128;

  for (int k0 = 0; k0 < Kd; k0 += BK) {
#pragma unroll
    for (int m = 0; m < CPTA; ++m) {
      int c = t + m * T;
      int rw = chunk_row(c);
      __builtin_amdgcn_global_load_lds(
          (const __attribute__((address_space(1))) void*)(Ab + (rowA + rw) * lda + k0 + chunk_gofs(c, rw)),
          (__attribute__((address_space(3))) void*)(As + c * 8), 16, 0, 0);
    }
#pragma unroll
    for (int m = 0; m < CPTB; ++m) {
      int c = t + m * T;
      int rw = chunk_row(c);
      __builtin_amdgcn_global_load_lds(
          (const __attribute__((address_space(1))) void*)(Bb + (rowB + rw) * ldb + k0 + chunk_gofs(c, rw)),
          (__attribute__((address_space(3))) void*)(Bs + c * 8), 16, 0, 0);
    }
    __syncthreads();

#pragma unroll
    for (int ks = 0; ks < BK / 32; ++ks) {
      bf16x8 af[4], bfr[4];
#pragma unroll
      for (int mt = 0; mt < 4; ++mt) {
        int tr = wm * 64 + mt * 16 + r;
        int sl;
        if constexpr (BK == 32) sl = q ^ ((tr >> 1) & 3);
        else sl = (ks * 4 + q) ^ (tr & 7);
        af[mt] = *(const bf16x8*)&As[tr * BK + sl * 8];
      }
#pragma unroll
      for (int nt = 0; nt < 4; ++nt) {
        int tr = wn * 64 + nt * 16 + r;
        int sl;
        if constexpr (BK == 32) sl = q ^ ((tr >> 1) & 3);
        else sl = (ks * 4 + q) ^ (tr & 7);
        bfr[nt] = *(const bf16x8*)&Bs[tr * BK + sl * 8];
      }
#pragma unroll
      for (int mt = 0; mt < 4; ++mt)
#pragma unroll
        for (int nt = 0; nt < 4; ++nt)
          acc[mt][nt] = __builtin_amdgcn_mfma_f32_16x16x32_bf16(
              bfr[nt], af[mt], acc[mt][nt], 0, 0, 0);
    }
    __syncthreads();
  }

  // Epilogue (operand-swapped): lane holds M-row = mt*16 + r, N-cols =
  // nt*16 + q*4 + j (consecutive) -> 8 B packed stores.
  const int colg0 = bn * 128 + wn * 64;
  const int rowg0 = bm * TM + wm * 64;
#pragma unroll
  for (int mt = 0; mt < 4; ++mt) {
    int row = rowg0 + mt * 16 + r;
#pragma unroll
    for (int nt = 0; nt < 4; ++nt) {
      int col = colg0 + nt * 16 + q * 4;
      const f32x4 bv = *(const f32x4*)&biasb[col];
      union {
        __hip_bfloat16 h[4];
        uint2 u;
      } pk;
#pragma unroll
      for (int j = 0; j < 4; ++j) {
        float v = acc[mt][nt][j] + bv[j];
        if (EPI == 1) v = fast_tanh(v);
        if (EPI == 2) v = fmaxf(v, 0.0f);
        pk.h[j] = __float2bfloat16(v);
      }
      *(uint2*)&Cb[(size_t)row * ldc + col] = pk.u;
    }
  }
}

// ---------------------------------------------------------------------------
// Final: zc laid [Bc][12][NH]; 2 waves per b (half-H each), partial Grams
// summed in LDS. Block = 256 thr = 2 b's.
// ---------------------------------------------------------------------------
__global__ __launch_bounds__(256) void final_gram(
    const __hip_bfloat16* __restrict__ zc, float* __restrict__ out, int Bc) {
  __shared__ float Gs[2][2][16][16];
  const int t = threadIdx.x;
  const int w = t >> 6, lane = t & 63;
  const int bi = w >> 1;
  const int hh = w & 1;
  const int b = blockIdx.x * 2 + bi;
  const int r = lane & 15;
  const int q = lane >> 4;

  const int rs = r < 12 ? r : 11;
  const __hip_bfloat16* base =
      zc + ((size_t)b * 12 + rs) * NH + hh * (NH / 2) + q * 8;

  f32x4 acc = {};
#pragma unroll
  for (int k0 = 0; k0 < NH / 2; k0 += 32) {
    bf16x8 a = {};
    if (r < 12) a = *(const bf16x8*)(base + k0);
    acc = __builtin_amdgcn_mfma_f32_16x16x32_bf16(a, a, acc, 0, 0, 0);
  }

#pragma unroll
  for (int j = 0; j < 4; ++j) Gs[bi][hh][q * 4 + j][r] = acc[j];
  __syncthreads();

  if (hh == 0) {
    float term = 0.0f;
    if (lane >= 1 && lane < 12) {
      const float(*G0)[16] = Gs[bi][0];
      const float(*G1)[16] = Gs[bi][1];
      float nrm[12];
#pragma unroll
      for (int i = 0; i < 12; ++i)
        nrm[i] = fmaxf(sqrtf(G0[i][i] + G1[i][i]), 1e-8f);
      const int k = lane;
      float pos = __expf((G0[0][k] + G1[0][k]) / (nrm[0] * nrm[k]));
      float neg = 0.0f;
#pragma unroll
      for (int l = 1; l < 12; ++l)
        if (l != k) neg += __expf((G0[k][l] + G1[k][l]) / (nrm[k] * nrm[l]));
      term = __logf(pos / (pos + neg));
    }
#pragma unroll
    for (int m = 1; m < 16; m <<= 1) term += __shfl_xor(term, m);
    if (lane == 0) out[b] = -term;
  }
}

// ---------------------------------------------------------------------------
extern "C" void kernel_launch(void* const* d_in, const int* in_sizes, int n_in,
                              void* d_out, int out_size, void* d_ws,
                              size_t ws_size, hipStream_t stream) {
  const float* x = (const float*)d_in[0];    // [B,D]
  const float* Wt1 = (const float*)d_in[1];  // [K,D,H]
  const float* bt1 = (const float*)d_in[2];  // [K,H]
  const float* Wt2 = (const float*)d_in[3];  // [K,H,D]
  const float* bt2 = (const float*)d_in[4];  // [K,D]
  const float* We1 = (const float*)d_in[5];  // [D,H]
  const float* be1 = (const float*)d_in[6];  // [H]
  const float* We2 = (const float*)d_in[7];  // [H,H]
  const float* be2 = (const float*)d_in[8];  // [H]
  float* out = (float*)d_out;                // [B]

  char* ws = (char*)d_ws;
  size_t off = 0;
  auto alloc = [&](size_t bytes) {
    void* p = ws + off;
    off += (bytes + 255) & ~(size_t)255;
    return p;
  };

  // Persistent bf16 weight transposes (~26 MB)
  __hip_bfloat16* Wt1t = (__hip_bfloat16*)alloc((size_t)NK * NH * ND * 2);  // [K,H,D]
  __hip_bfloat16* Wt2t = (__hip_bfloat16*)alloc((size_t)NK * ND * NH * 2);  // [K,D,H]
  __hip_bfloat16* We1t = (__hip_bfloat16*)alloc((size_t)NH * ND * 2);       // [H,D]
  __hip_bfloat16* We2t = (__hip_bfloat16*)alloc((size_t)NH * NH * 2);       // [H,H]
  const size_t wbytes = off;

  // Pick largest batch chunk Bc (ws known to land at 4096: ws in [227,278)MB).
  // zc ALIASES txc's region (txc dead after G3).
  int Bc = NB;
  while (Bc > 256) {
    size_t need = wbytes + 2 * ((size_t)12 * Bc * NH * 2) + 4096;
    if (need <= ws_size) break;
    Bc >>= 1;
  }
  __hip_bfloat16* region0 = (__hip_bfloat16*)alloc((size_t)12 * Bc * NH * 2);
  __hip_bfloat16* h1 = (__hip_bfloat16*)alloc((size_t)12 * Bc * NH * 2);
  __hip_bfloat16* txc = region0;  // [12, Bc, ND] during G1..G3
  __hip_bfloat16* zc = region0;   // [Bc, 12, NH] during G4..final

  // One-time: all weight transposes in ONE launch
  transpose_all<<<dim3(NH / 32, NH / 32, 2 * NK + 2), dim3(32, 8), 0,
                  stream>>>(Wt1, Wt2, We1, We2, Wt1t, Wt2t, We1t, We2t);

  for (int cs = 0; cs < NB; cs += Bc) {
    // 1) x chunk -> bf16 (slice 0 of txc)
    cvt_f32_bf16<<<(Bc * ND) / 256, 256, 0, stream>>>(
        x + (size_t)cs * ND, txc, Bc * ND);
    // 2) G1: hx_k = tanh(x @ Wt1[k] + bt1) -> h1 slices 0..10 (Kd=512,BK32)
    gemm_bt<1, 32, 128><<<dim3(Bc / 128, NH / 128, NK), 256, 0, stream>>>(
        txc, 0L, ND, Wt1t, (long)NH * ND, ND, bt1, (long)NH, h1,
        (long)Bc * NH, NH, ND);
    // 3) G2: tx_k = hx_k @ Wt2[k] + bt2 -> txc slices 1..11 (Kd=1024,BK64)
    gemm_bt<3, 64, 128><<<dim3(Bc / 128, ND / 128, NK), 256, 0, stream>>>(
        h1, (long)Bc * NH, NH, Wt2t, (long)ND * NH, NH, bt2, (long)ND,
        txc + (size_t)Bc * ND, (long)Bc * ND, ND, NH);
    // 4) G3: e1_s = relu(tx_s @ We1 + be1) -> h1 slices 0..11 (Kd=512,BK32)
    gemm_bt<2, 32, 128><<<dim3(Bc / 128, NH / 128, 12), 256, 0, stream>>>(
        txc, (long)Bc * ND, ND, We1t, 0L, ND, be1, 0L, h1, (long)Bc * NH,
        NH, ND);
    // 5) G4: z_s -> zc [b][s][h] (sCz=NH, ldc=12NH). R9: TM=256 tile —
    //    64 MFMAs per barrier-pair at 48 KB LDS.
    gemm_bt<3, 64, 256><<<dim3(Bc / 256, NH / 128, 12), 512, 0, stream>>>(
        h1, (long)Bc * NH, NH, We2t, 0L, NH, be2, 0L, zc, (long)NH,
        12 * NH, NH);
    // 6) final score
    final_gram<<<Bc / 2, 256, 0, stream>>>(zc, out + cs, Bc);
  }
}

// Round 10
// 817.943 us; speedup vs baseline: 1.6270x; 1.0647x over previous
//
#include <hip/hip_runtime.h>
#include <hip/hip_bf16.h>
#include <cstdint>
#include <cstddef>

// Problem constants (NeuTraLAD): B=8192, D=512, H=1024, K=11 views.
#define NB 8192
#define ND 512
#define NH 1024
#define NK 11

typedef __bf16 bf16x8 __attribute__((ext_vector_type(8)));
typedef float f32x4 __attribute__((ext_vector_type(4)));

// ---------------------------------------------------------------------------
// Convert f32 -> bf16 elementwise
// ---------------------------------------------------------------------------
__global__ void cvt_f32_bf16(const float* __restrict__ in,
                             __hip_bfloat16* __restrict__ out, int n) {
  int i = blockIdx.x * blockDim.x + threadIdx.x;
  if (i < n) out[i] = __float2bfloat16(in[i]);
}

// ---------------------------------------------------------------------------
// ONE preamble launch: all four weight transposes f32 [R,C] -> bf16 [C,R].
// z 0..10 = Wt1 slices, 11..21 = Wt2 slices, 22 = We1, 23 = We2.
// ---------------------------------------------------------------------------
__global__ void transpose_all(const float* __restrict__ Wt1,
                              const float* __restrict__ Wt2,
                              const float* __restrict__ We1,
                              const float* __restrict__ We2,
                              __hip_bfloat16* __restrict__ Wt1t,
                              __hip_bfloat16* __restrict__ Wt2t,
                              __hip_bfloat16* __restrict__ We1t,
                              __hip_bfloat16* __restrict__ We2t) {
  __shared__ float tile[32][33];
  const int z = blockIdx.z;
  int R, C;
  const float* inb;
  __hip_bfloat16* outb;
  if (z < NK) {
    R = ND; C = NH;
    inb = Wt1 + (size_t)z * ND * NH;
    outb = Wt1t + (size_t)z * ND * NH;
  } else if (z < 2 * NK) {
    R = NH; C = ND;
    inb = Wt2 + (size_t)(z - NK) * NH * ND;
    outb = Wt2t + (size_t)(z - NK) * NH * ND;
  } else if (z == 2 * NK) {
    R = ND; C = NH;
    inb = We1; outb = We1t;
  } else {
    R = NH; C = NH;
    inb = We2; outb = We2t;
  }
  int cx = blockIdx.x * 32 + threadIdx.x;
  int ry = blockIdx.y * 32;
  if (blockIdx.x * 32 >= C || ry >= R) return;  // uniform early-out
  for (int j = threadIdx.y; j < 32; j += 8)
    tile[j][threadIdx.x] = inb[(size_t)(ry + j) * C + cx];
  __syncthreads();
  int ox = ry + threadIdx.x;
  int oy = blockIdx.x * 32;
  for (int j = threadIdx.y; j < 32; j += 8)
    outb[(size_t)(oy + j) * R + ox] = __float2bfloat16(tile[threadIdx.x][j]);
}

__device__ __forceinline__ float fast_tanh(float x) {
  float e = __expf(2.0f * x);
  return 1.0f - 2.0f / (e + 1.0f);
}

// ---------------------------------------------------------------------------
// MFMA GEMM (NT): C[M,N] = act(A[M,Kd] * Bt[N,Kd]^T + bias[N])
// TM x 128 block tile. R9 measured: TM=256 (512 thr, 8 waves 4x2) lifts
// MfmaUtil 29->41 and G4 148->107 us (compute/staging 85 vs 64, half the
// barrier-pairs per FLOP). R10: TM=256 for ALL gemms.
// [R7 lesson: do NOT re-attempt direct-B / single-barrier pipelining.]
// BK per shape [R4/R5]: Kd=512 -> BK=32, Kd=1024 -> BK=64.
// Grid x = row panel (XCD affinity: FETCH 198->41MB, R4). XOR chunk
// swizzles (measured conflict-free R5-R9). MFMA operands swapped -> lane
// holds 4 consecutive cols of C -> 8 B packed stores.
// EPI: 1 = tanh->bf16, 2 = relu->bf16, 3 = plain->bf16
// ---------------------------------------------------------------------------
template <int EPI, int BK, int TM>
__global__ __launch_bounds__(TM * 2) void gemm_bt(
    const __hip_bfloat16* __restrict__ A, long sAz, int lda,
    const __hip_bfloat16* __restrict__ Bt, long sBz, int ldb,
    const float* __restrict__ bias, long sBiasZ,
    __hip_bfloat16* __restrict__ C, long sCz, int ldc, int Kd) {
  __shared__ __align__(16) __hip_bfloat16 As[TM * BK];
  __shared__ __align__(16) __hip_bfloat16 Bs[128 * BK];

  const int z = blockIdx.z;
  const __hip_bfloat16* Ab = A + (size_t)z * sAz;
  const __hip_bfloat16* Bb = Bt + (size_t)z * sBz;
  const float* biasb = bias + (size_t)z * sBiasZ;
  __hip_bfloat16* Cb = C + (size_t)z * sCz;

  const int bm = blockIdx.x, bn = blockIdx.y;  // x = row panel (XCD affinity)
  const int t = threadIdx.x;
  constexpr int T = TM * 2;  // threads
  const int lane = t & 63, w = t >> 6;
  const int wm = w >> 1, wn = w & 1;  // wm 0..TM/64-1, wn 0..1
  const int r = lane & 15, q = lane >> 4;

  f32x4 acc[4][4] = {};

  // Staging chunk->(row, global-offset) with XOR swizzle (self-inverse).
  auto chunk_row = [&](int c) {
    return (BK == 32) ? (c >> 2) : (c >> 3);
  };
  auto chunk_gofs = [&](int c, int row) {
    return (BK == 32) ? ((((c & 3) ^ ((row >> 1) & 3)) * 8))
                      : ((((c & 7) ^ (row & 7)) * 8));
  };
  constexpr int CPTA = BK / 16;          // A chunks per thread (TM*BK/8/T)
  constexpr int CPTB = 8 * BK / TM;      // B chunks per thread (128*BK/8/T)
  const size_t rowA = (size_t)bm * TM, rowB = (size_t)bn * 128;

  for (int k0 = 0; k0 < Kd; k0 += BK) {
#pragma unroll
    for (int m = 0; m < CPTA; ++m) {
      int c = t + m * T;
      int rw = chunk_row(c);
      __builtin_amdgcn_global_load_lds(
          (const __attribute__((address_space(1))) void*)(Ab + (rowA + rw) * lda + k0 + chunk_gofs(c, rw)),
          (__attribute__((address_space(3))) void*)(As + c * 8), 16, 0, 0);
    }
#pragma unroll
    for (int m = 0; m < CPTB; ++m) {
      int c = t + m * T;
      int rw = chunk_row(c);
      __builtin_amdgcn_global_load_lds(
          (const __attribute__((address_space(1))) void*)(Bb + (rowB + rw) * ldb + k0 + chunk_gofs(c, rw)),
          (__attribute__((address_space(3))) void*)(Bs + c * 8), 16, 0, 0);
    }
    __syncthreads();

#pragma unroll
    for (int ks = 0; ks < BK / 32; ++ks) {
      bf16x8 af[4], bfr[4];
#pragma unroll
      for (int mt = 0; mt < 4; ++mt) {
        int tr = wm * 64 + mt * 16 + r;
        int sl;
        if constexpr (BK == 32) sl = q ^ ((tr >> 1) & 3);
        else sl = (ks * 4 + q) ^ (tr & 7);
        af[mt] = *(const bf16x8*)&As[tr * BK + sl * 8];
      }
#pragma unroll
      for (int nt = 0; nt < 4; ++nt) {
        int tr = wn * 64 + nt * 16 + r;
        int sl;
        if constexpr (BK == 32) sl = q ^ ((tr >> 1) & 3);
        else sl = (ks * 4 + q) ^ (tr & 7);
        bfr[nt] = *(const bf16x8*)&Bs[tr * BK + sl * 8];
      }
#pragma unroll
      for (int mt = 0; mt < 4; ++mt)
#pragma unroll
        for (int nt = 0; nt < 4; ++nt)
          acc[mt][nt] = __builtin_amdgcn_mfma_f32_16x16x32_bf16(
              bfr[nt], af[mt], acc[mt][nt], 0, 0, 0);
    }
    __syncthreads();
  }

  // Epilogue (operand-swapped): lane holds M-row = mt*16 + r, N-cols =
  // nt*16 + q*4 + j (consecutive) -> 8 B packed stores.
  const int colg0 = bn * 128 + wn * 64;
  const int rowg0 = bm * TM + wm * 64;
#pragma unroll
  for (int mt = 0; mt < 4; ++mt) {
    int row = rowg0 + mt * 16 + r;
#pragma unroll
    for (int nt = 0; nt < 4; ++nt) {
      int col = colg0 + nt * 16 + q * 4;
      const f32x4 bv = *(const f32x4*)&biasb[col];
      union {
        __hip_bfloat16 h[4];
        uint2 u;
      } pk;
#pragma unroll
      for (int j = 0; j < 4; ++j) {
        float v = acc[mt][nt][j] + bv[j];
        if (EPI == 1) v = fast_tanh(v);
        if (EPI == 2) v = fmaxf(v, 0.0f);
        pk.h[j] = __float2bfloat16(v);
      }
      *(uint2*)&Cb[(size_t)row * ldc + col] = pk.u;
    }
  }
}

// ---------------------------------------------------------------------------
// Final: zc laid [Bc][12][NH]; 2 waves per b (half-H each), partial Grams
// summed in LDS. Block = 256 thr = 2 b's.
// ---------------------------------------------------------------------------
__global__ __launch_bounds__(256) void final_gram(
    const __hip_bfloat16* __restrict__ zc, float* __restrict__ out, int Bc) {
  __shared__ float Gs[2][2][16][16];
  const int t = threadIdx.x;
  const int w = t >> 6, lane = t & 63;
  const int bi = w >> 1;
  const int hh = w & 1;
  const int b = blockIdx.x * 2 + bi;
  const int r = lane & 15;
  const int q = lane >> 4;

  const int rs = r < 12 ? r : 11;
  const __hip_bfloat16* base =
      zc + ((size_t)b * 12 + rs) * NH + hh * (NH / 2) + q * 8;

  f32x4 acc = {};
#pragma unroll
  for (int k0 = 0; k0 < NH / 2; k0 += 32) {
    bf16x8 a = {};
    if (r < 12) a = *(const bf16x8*)(base + k0);
    acc = __builtin_amdgcn_mfma_f32_16x16x32_bf16(a, a, acc, 0, 0, 0);
  }

#pragma unroll
  for (int j = 0; j < 4; ++j) Gs[bi][hh][q * 4 + j][r] = acc[j];
  __syncthreads();

  if (hh == 0) {
    float term = 0.0f;
    if (lane >= 1 && lane < 12) {
      const float(*G0)[16] = Gs[bi][0];
      const float(*G1)[16] = Gs[bi][1];
      float nrm[12];
#pragma unroll
      for (int i = 0; i < 12; ++i)
        nrm[i] = fmaxf(sqrtf(G0[i][i] + G1[i][i]), 1e-8f);
      const int k = lane;
      float pos = __expf((G0[0][k] + G1[0][k]) / (nrm[0] * nrm[k]));
      float neg = 0.0f;
#pragma unroll
      for (int l = 1; l < 12; ++l)
        if (l != k) neg += __expf((G0[k][l] + G1[k][l]) / (nrm[k] * nrm[l]));
      term = __logf(pos / (pos + neg));
    }
#pragma unroll
    for (int m = 1; m < 16; m <<= 1) term += __shfl_xor(term, m);
    if (lane == 0) out[b] = -term;
  }
}

// ---------------------------------------------------------------------------
extern "C" void kernel_launch(void* const* d_in, const int* in_sizes, int n_in,
                              void* d_out, int out_size, void* d_ws,
                              size_t ws_size, hipStream_t stream) {
  const float* x = (const float*)d_in[0];    // [B,D]
  const float* Wt1 = (const float*)d_in[1];  // [K,D,H]
  const float* bt1 = (const float*)d_in[2];  // [K,H]
  const float* Wt2 = (const float*)d_in[3];  // [K,H,D]
  const float* bt2 = (const float*)d_in[4];  // [K,D]
  const float* We1 = (const float*)d_in[5];  // [D,H]
  const float* be1 = (const float*)d_in[6];  // [H]
  const float* We2 = (const float*)d_in[7];  // [H,H]
  const float* be2 = (const float*)d_in[8];  // [H]
  float* out = (float*)d_out;                // [B]

  char* ws = (char*)d_ws;
  size_t off = 0;
  auto alloc = [&](size_t bytes) {
    void* p = ws + off;
    off += (bytes + 255) & ~(size_t)255;
    return p;
  };

  // Persistent bf16 weight transposes (~26 MB)
  __hip_bfloat16* Wt1t = (__hip_bfloat16*)alloc((size_t)NK * NH * ND * 2);  // [K,H,D]
  __hip_bfloat16* Wt2t = (__hip_bfloat16*)alloc((size_t)NK * ND * NH * 2);  // [K,D,H]
  __hip_bfloat16* We1t = (__hip_bfloat16*)alloc((size_t)NH * ND * 2);       // [H,D]
  __hip_bfloat16* We2t = (__hip_bfloat16*)alloc((size_t)NH * NH * 2);       // [H,H]
  const size_t wbytes = off;

  // Pick largest batch chunk Bc (ws in [227,278) MB -> Bc=4096).
  // zc ALIASES txc's region (txc dead after G3).
  int Bc = NB;
  while (Bc > 256) {
    size_t need = wbytes + 2 * ((size_t)12 * Bc * NH * 2) + 4096;
    if (need <= ws_size) break;
    Bc >>= 1;
  }
  __hip_bfloat16* region0 = (__hip_bfloat16*)alloc((size_t)12 * Bc * NH * 2);
  __hip_bfloat16* h1 = (__hip_bfloat16*)alloc((size_t)12 * Bc * NH * 2);
  __hip_bfloat16* txc = region0;  // [12, Bc, ND] during G1..G3
  __hip_bfloat16* zc = region0;   // [Bc, 12, NH] during G4..final

  // One-time: all weight transposes in ONE launch
  transpose_all<<<dim3(NH / 32, NH / 32, 2 * NK + 2), dim3(32, 8), 0,
                  stream>>>(Wt1, Wt2, We1, We2, Wt1t, Wt2t, We1t, We2t);

  for (int cs = 0; cs < NB; cs += Bc) {
    // 1) x chunk -> bf16 (slice 0 of txc)
    cvt_f32_bf16<<<(Bc * ND) / 256, 256, 0, stream>>>(
        x + (size_t)cs * ND, txc, Bc * ND);
    // 2) G1: hx_k = tanh(x @ Wt1[k] + bt1) -> h1 slices 0..10
    //    (Kd=512, BK32, TM256 — 24 KB LDS)
    gemm_bt<1, 32, 256><<<dim3(Bc / 256, NH / 128, NK), 512, 0, stream>>>(
        txc, 0L, ND, Wt1t, (long)NH * ND, ND, bt1, (long)NH, h1,
        (long)Bc * NH, NH, ND);
    // 3) G2: tx_k = hx_k @ Wt2[k] + bt2 -> txc slices 1..11
    //    (Kd=1024, BK64, TM256)
    gemm_bt<3, 64, 256><<<dim3(Bc / 256, ND / 128, NK), 512, 0, stream>>>(
        h1, (long)Bc * NH, NH, Wt2t, (long)ND * NH, NH, bt2, (long)ND,
        txc + (size_t)Bc * ND, (long)Bc * ND, ND, NH);
    // 4) G3: e1_s = relu(tx_s @ We1 + be1) -> h1 slices 0..11
    //    (Kd=512, BK32, TM256)
    gemm_bt<2, 32, 256><<<dim3(Bc / 256, NH / 128, 12), 512, 0, stream>>>(
        txc, (long)Bc * ND, ND, We1t, 0L, ND, be1, 0L, h1, (long)Bc * NH,
        NH, ND);
    // 5) G4: z_s -> zc [b][s][h] (sCz=NH, ldc=12NH; Kd=1024, BK64, TM256)
    gemm_bt<3, 64, 256><<<dim3(Bc / 256, NH / 128, 12), 512, 0, stream>>>(
        h1, (long)Bc * NH, NH, We2t, 0L, NH, be2, 0L, zc, (long)NH,
        12 * NH, NH);
    // 6) final score
    final_gram<<<Bc / 2, 256, 0, stream>>>(zc, out + cs, Bc);
  }
}

// Round 11
// 794.153 us; speedup vs baseline: 1.6757x; 1.0300x over previous
//
#include <hip/hip_runtime.h>
#include <hip/hip_bf16.h>
#include <cstdint>
#include <cstddef>

// Problem constants (NeuTraLAD): B=8192, D=512, H=1024, K=11 views.
#define NB 8192
#define ND 512
#define NH 1024
#define NK 11

typedef __bf16 bf16x8 __attribute__((ext_vector_type(8)));
typedef float f32x4 __attribute__((ext_vector_type(4)));

// ---------------------------------------------------------------------------
// Convert f32 -> bf16 elementwise
// ---------------------------------------------------------------------------
__global__ void cvt_f32_bf16(const float* __restrict__ in,
                             __hip_bfloat16* __restrict__ out, int n) {
  int i = blockIdx.x * blockDim.x + threadIdx.x;
  if (i < n) out[i] = __float2bfloat16(in[i]);
}

// ---------------------------------------------------------------------------
// ONE preamble launch: all four weight transposes f32 [R,C] -> bf16 [C,R].
// z 0..10 = Wt1 slices, 11..21 = Wt2 slices, 22 = We1, 23 = We2.
// ---------------------------------------------------------------------------
__global__ void transpose_all(const float* __restrict__ Wt1,
                              const float* __restrict__ Wt2,
                              const float* __restrict__ We1,
                              const float* __restrict__ We2,
                              __hip_bfloat16* __restrict__ Wt1t,
                              __hip_bfloat16* __restrict__ Wt2t,
                              __hip_bfloat16* __restrict__ We1t,
                              __hip_bfloat16* __restrict__ We2t) {
  __shared__ float tile[32][33];
  const int z = blockIdx.z;
  int R, C;
  const float* inb;
  __hip_bfloat16* outb;
  if (z < NK) {
    R = ND; C = NH;
    inb = Wt1 + (size_t)z * ND * NH;
    outb = Wt1t + (size_t)z * ND * NH;
  } else if (z < 2 * NK) {
    R = NH; C = ND;
    inb = Wt2 + (size_t)(z - NK) * NH * ND;
    outb = Wt2t + (size_t)(z - NK) * NH * ND;
  } else if (z == 2 * NK) {
    R = ND; C = NH;
    inb = We1; outb = We1t;
  } else {
    R = NH; C = NH;
    inb = We2; outb = We2t;
  }
  int cx = blockIdx.x * 32 + threadIdx.x;
  int ry = blockIdx.y * 32;
  if (blockIdx.x * 32 >= C || ry >= R) return;  // uniform early-out
  for (int j = threadIdx.y; j < 32; j += 8)
    tile[j][threadIdx.x] = inb[(size_t)(ry + j) * C + cx];
  __syncthreads();
  int ox = ry + threadIdx.x;
  int oy = blockIdx.x * 32;
  for (int j = threadIdx.y; j < 32; j += 8)
    outb[(size_t)(oy + j) * R + ox] = __float2bfloat16(tile[threadIdx.x][j]);
}

__device__ __forceinline__ float fast_tanh(float x) {
  float e = __expf(2.0f * x);
  return 1.0f - 2.0f / (e + 1.0f);
}

// ---------------------------------------------------------------------------
// MFMA GEMM (NT): C[M,N] = act(A[M,Kd] * Bt[N,Kd]^T + bias[N])
// TM x 128 block tile. R9/R10 measured: TM=256 (512 thr, 8 waves 4x2)
// lifts MfmaUtil 29->41.5 (G4 963 TF). R11: BK=64 for ALL gemms — at
// TM=256 the R5 BK64 occupancy penalty is gone and every barrier-pair
// carries 32 MFMAs/wave (the measured-best G4 config).
// [R7 lesson: do NOT re-attempt direct-B / single-barrier pipelining.]
// Grid x = row panel (XCD affinity: FETCH 198->41MB, R4). XOR chunk
// swizzles (measured conflict-free R5-R10). MFMA operands swapped -> lane
// holds 4 consecutive cols of C -> 8 B packed stores.
// EPI: 1 = tanh->bf16, 2 = relu->bf16, 3 = plain->bf16
// ---------------------------------------------------------------------------
template <int EPI, int BK, int TM>
__global__ __launch_bounds__(TM * 2) void gemm_bt(
    const __hip_bfloat16* __restrict__ A, long sAz, int lda,
    const __hip_bfloat16* __restrict__ Bt, long sBz, int ldb,
    const float* __restrict__ bias, long sBiasZ,
    __hip_bfloat16* __restrict__ C, long sCz, int ldc, int Kd) {
  __shared__ __align__(16) __hip_bfloat16 As[TM * BK];
  __shared__ __align__(16) __hip_bfloat16 Bs[128 * BK];

  const int z = blockIdx.z;
  const __hip_bfloat16* Ab = A + (size_t)z * sAz;
  const __hip_bfloat16* Bb = Bt + (size_t)z * sBz;
  const float* biasb = bias + (size_t)z * sBiasZ;
  __hip_bfloat16* Cb = C + (size_t)z * sCz;

  const int bm = blockIdx.x, bn = blockIdx.y;  // x = row panel (XCD affinity)
  const int t = threadIdx.x;
  constexpr int T = TM * 2;  // threads
  const int lane = t & 63, w = t >> 6;
  const int wm = w >> 1, wn = w & 1;  // wm 0..TM/64-1, wn 0..1
  const int r = lane & 15, q = lane >> 4;

  f32x4 acc[4][4] = {};

  // Staging chunk->(row, global-offset) with XOR swizzle (self-inverse).
  auto chunk_row = [&](int c) {
    return (BK == 32) ? (c >> 2) : (c >> 3);
  };
  auto chunk_gofs = [&](int c, int row) {
    return (BK == 32) ? ((((c & 3) ^ ((row >> 1) & 3)) * 8))
                      : ((((c & 7) ^ (row & 7)) * 8));
  };
  constexpr int CPTA = BK / 16;          // A chunks per thread (TM*BK/8/T)
  constexpr int CPTB = 8 * BK / TM;      // B chunks per thread (128*BK/8/T)
  const size_t rowA = (size_t)bm * TM, rowB = (size_t)bn * 128;

  for (int k0 = 0; k0 < Kd; k0 += BK) {
#pragma unroll
    for (int m = 0; m < CPTA; ++m) {
      int c = t + m * T;
      int rw = chunk_row(c);
      __builtin_amdgcn_global_load_lds(
          (const __attribute__((address_space(1))) void*)(Ab + (rowA + rw) * lda + k0 + chunk_gofs(c, rw)),
          (__attribute__((address_space(3))) void*)(As + c * 8), 16, 0, 0);
    }
#pragma unroll
    for (int m = 0; m < CPTB; ++m) {
      int c = t + m * T;
      int rw = chunk_row(c);
      __builtin_amdgcn_global_load_lds(
          (const __attribute__((address_space(1))) void*)(Bb + (rowB + rw) * ldb + k0 + chunk_gofs(c, rw)),
          (__attribute__((address_space(3))) void*)(Bs + c * 8), 16, 0, 0);
    }
    __syncthreads();

#pragma unroll
    for (int ks = 0; ks < BK / 32; ++ks) {
      bf16x8 af[4], bfr[4];
#pragma unroll
      for (int mt = 0; mt < 4; ++mt) {
        int tr = wm * 64 + mt * 16 + r;
        int sl;
        if constexpr (BK == 32) sl = q ^ ((tr >> 1) & 3);
        else sl = (ks * 4 + q) ^ (tr & 7);
        af[mt] = *(const bf16x8*)&As[tr * BK + sl * 8];
      }
#pragma unroll
      for (int nt = 0; nt < 4; ++nt) {
        int tr = wn * 64 + nt * 16 + r;
        int sl;
        if constexpr (BK == 32) sl = q ^ ((tr >> 1) & 3);
        else sl = (ks * 4 + q) ^ (tr & 7);
        bfr[nt] = *(const bf16x8*)&Bs[tr * BK + sl * 8];
      }
#pragma unroll
      for (int mt = 0; mt < 4; ++mt)
#pragma unroll
        for (int nt = 0; nt < 4; ++nt)
          acc[mt][nt] = __builtin_amdgcn_mfma_f32_16x16x32_bf16(
              bfr[nt], af[mt], acc[mt][nt], 0, 0, 0);
    }
    __syncthreads();
  }

  // Epilogue (operand-swapped): lane holds M-row = mt*16 + r, N-cols =
  // nt*16 + q*4 + j (consecutive) -> 8 B packed stores.
  const int colg0 = bn * 128 + wn * 64;
  const int rowg0 = bm * TM + wm * 64;
#pragma unroll
  for (int mt = 0; mt < 4; ++mt) {
    int row = rowg0 + mt * 16 + r;
#pragma unroll
    for (int nt = 0; nt < 4; ++nt) {
      int col = colg0 + nt * 16 + q * 4;
      const f32x4 bv = *(const f32x4*)&biasb[col];
      union {
        __hip_bfloat16 h[4];
        uint2 u;
      } pk;
#pragma unroll
      for (int j = 0; j < 4; ++j) {
        float v = acc[mt][nt][j] + bv[j];
        if (EPI == 1) v = fast_tanh(v);
        if (EPI == 2) v = fmaxf(v, 0.0f);
        pk.h[j] = __float2bfloat16(v);
      }
      *(uint2*)&Cb[(size_t)row * ldc + col] = pk.u;
    }
  }
}

// ---------------------------------------------------------------------------
// Final: zc laid [Bc][12][NH]; 2 waves per b (half-H each), partial Grams
// summed in LDS. Block = 256 thr = 2 b's.
// ---------------------------------------------------------------------------
__global__ __launch_bounds__(256) void final_gram(
    const __hip_bfloat16* __restrict__ zc, float* __restrict__ out, int Bc) {
  __shared__ float Gs[2][2][16][16];
  const int t = threadIdx.x;
  const int w = t >> 6, lane = t & 63;
  const int bi = w >> 1;
  const int hh = w & 1;
  const int b = blockIdx.x * 2 + bi;
  const int r = lane & 15;
  const int q = lane >> 4;

  const int rs = r < 12 ? r : 11;
  const __hip_bfloat16* base =
      zc + ((size_t)b * 12 + rs) * NH + hh * (NH / 2) + q * 8;

  f32x4 acc = {};
#pragma unroll
  for (int k0 = 0; k0 < NH / 2; k0 += 32) {
    bf16x8 a = {};
    if (r < 12) a = *(const bf16x8*)(base + k0);
    acc = __builtin_amdgcn_mfma_f32_16x16x32_bf16(a, a, acc, 0, 0, 0);
  }

#pragma unroll
  for (int j = 0; j < 4; ++j) Gs[bi][hh][q * 4 + j][r] = acc[j];
  __syncthreads();

  if (hh == 0) {
    float term = 0.0f;
    if (lane >= 1 && lane < 12) {
      const float(*G0)[16] = Gs[bi][0];
      const float(*G1)[16] = Gs[bi][1];
      float nrm[12];
#pragma unroll
      for (int i = 0; i < 12; ++i)
        nrm[i] = fmaxf(sqrtf(G0[i][i] + G1[i][i]), 1e-8f);
      const int k = lane;
      float pos = __expf((G0[0][k] + G1[0][k]) / (nrm[0] * nrm[k]));
      float neg = 0.0f;
#pragma unroll
      for (int l = 1; l < 12; ++l)
        if (l != k) neg += __expf((G0[k][l] + G1[k][l]) / (nrm[k] * nrm[l]));
      term = __logf(pos / (pos + neg));
    }
#pragma unroll
    for (int m = 1; m < 16; m <<= 1) term += __shfl_xor(term, m);
    if (lane == 0) out[b] = -term;
  }
}

// ---------------------------------------------------------------------------
extern "C" void kernel_launch(void* const* d_in, const int* in_sizes, int n_in,
                              void* d_out, int out_size, void* d_ws,
                              size_t ws_size, hipStream_t stream) {
  const float* x = (const float*)d_in[0];    // [B,D]
  const float* Wt1 = (const float*)d_in[1];  // [K,D,H]
  const float* bt1 = (const float*)d_in[2];  // [K,H]
  const float* Wt2 = (const float*)d_in[3];  // [K,H,D]
  const float* bt2 = (const float*)d_in[4];  // [K,D]
  const float* We1 = (const float*)d_in[5];  // [D,H]
  const float* be1 = (const float*)d_in[6];  // [H]
  const float* We2 = (const float*)d_in[7];  // [H,H]
  const float* be2 = (const float*)d_in[8];  // [H]
  float* out = (float*)d_out;                // [B]

  char* ws = (char*)d_ws;
  size_t off = 0;
  auto alloc = [&](size_t bytes) {
    void* p = ws + off;
    off += (bytes + 255) & ~(size_t)255;
    return p;
  };

  // Persistent bf16 weight transposes (~26 MB)
  __hip_bfloat16* Wt1t = (__hip_bfloat16*)alloc((size_t)NK * NH * ND * 2);  // [K,H,D]
  __hip_bfloat16* Wt2t = (__hip_bfloat16*)alloc((size_t)NK * ND * NH * 2);  // [K,D,H]
  __hip_bfloat16* We1t = (__hip_bfloat16*)alloc((size_t)NH * ND * 2);       // [H,D]
  __hip_bfloat16* We2t = (__hip_bfloat16*)alloc((size_t)NH * NH * 2);       // [H,H]
  const size_t wbytes = off;

  // Pick largest batch chunk Bc (ws in [228,253) MB -> Bc=4096).
  // zc ALIASES txc's region (txc dead after G3).
  int Bc = NB;
  while (Bc > 256) {
    size_t need = wbytes + 2 * ((size_t)12 * Bc * NH * 2) + 4096;
    if (need <= ws_size) break;
    Bc >>= 1;
  }
  __hip_bfloat16* region0 = (__hip_bfloat16*)alloc((size_t)12 * Bc * NH * 2);
  __hip_bfloat16* h1 = (__hip_bfloat16*)alloc((size_t)12 * Bc * NH * 2);
  __hip_bfloat16* txc = region0;  // [12, Bc, ND] during G1..G3
  __hip_bfloat16* zc = region0;   // [Bc, 12, NH] during G4..final

  // One-time: all weight transposes in ONE launch
  transpose_all<<<dim3(NH / 32, NH / 32, 2 * NK + 2), dim3(32, 8), 0,
                  stream>>>(Wt1, Wt2, We1, We2, Wt1t, Wt2t, We1t, We2t);

  for (int cs = 0; cs < NB; cs += Bc) {
    // 1) x chunk -> bf16 (slice 0 of txc)
    cvt_f32_bf16<<<(Bc * ND) / 256, 256, 0, stream>>>(
        x + (size_t)cs * ND, txc, Bc * ND);
    // 2) G1: hx_k = tanh(x @ Wt1[k] + bt1) -> h1 slices 0..10
    //    (Kd=512, BK64, TM256 — R11)
    gemm_bt<1, 64, 256><<<dim3(Bc / 256, NH / 128, NK), 512, 0, stream>>>(
        txc, 0L, ND, Wt1t, (long)NH * ND, ND, bt1, (long)NH, h1,
        (long)Bc * NH, NH, ND);
    // 3) G2: tx_k = hx_k @ Wt2[k] + bt2 -> txc slices 1..11
    //    (Kd=1024, BK64, TM256)
    gemm_bt<3, 64, 256><<<dim3(Bc / 256, ND / 128, NK), 512, 0, stream>>>(
        h1, (long)Bc * NH, NH, Wt2t, (long)ND * NH, NH, bt2, (long)ND,
        txc + (size_t)Bc * ND, (long)Bc * ND, ND, NH);
    // 4) G3: e1_s = relu(tx_s @ We1 + be1) -> h1 slices 0..11
    //    (Kd=512, BK64, TM256 — R11)
    gemm_bt<2, 64, 256><<<dim3(Bc / 256, NH / 128, 12), 512, 0, stream>>>(
        txc, (long)Bc * ND, ND, We1t, 0L, ND, be1, 0L, h1, (long)Bc * NH,
        NH, ND);
    // 5) G4: z_s -> zc [b][s][h] (sCz=NH, ldc=12NH; Kd=1024, BK64, TM256)
    gemm_bt<3, 64, 256><<<dim3(Bc / 256, NH / 128, 12), 512, 0, stream>>>(
        h1, (long)Bc * NH, NH, We2t, 0L, NH, be2, 0L, zc, (long)NH,
        12 * NH, NH);
    // 6) final score
    final_gram<<<Bc / 2, 256, 0, stream>>>(zc, out + cs, Bc);
  }
}

// Round 13
// 774.462 us; speedup vs baseline: 1.7183x; 1.0254x over previous
//
#include <hip/hip_runtime.h>
#include <hip/hip_bf16.h>
#include <cstdint>
#include <cstddef>

// Problem constants (NeuTraLAD): B=8192, D=512, H=1024, K=11 views.
#define NB 8192
#define ND 512
#define NH 1024
#define NK 11

typedef __bf16 bf16x8 __attribute__((ext_vector_type(8)));
typedef float f32x4 __attribute__((ext_vector_type(4)));

// ---------------------------------------------------------------------------
// Convert f32 -> bf16 elementwise
// ---------------------------------------------------------------------------
__global__ void cvt_f32_bf16(const float* __restrict__ in,
                             __hip_bfloat16* __restrict__ out, int n) {
  int i = blockIdx.x * blockDim.x + threadIdx.x;
  if (i < n) out[i] = __float2bfloat16(in[i]);
}

// ---------------------------------------------------------------------------
// ONE preamble launch: all four weight transposes f32 [R,C] -> bf16 [C,R].
// z 0..10 = Wt1 slices, 11..21 = Wt2 slices, 22 = We1, 23 = We2.
// ---------------------------------------------------------------------------
__global__ void transpose_all(const float* __restrict__ Wt1,
                              const float* __restrict__ Wt2,
                              const float* __restrict__ We1,
                              const float* __restrict__ We2,
                              __hip_bfloat16* __restrict__ Wt1t,
                              __hip_bfloat16* __restrict__ Wt2t,
                              __hip_bfloat16* __restrict__ We1t,
                              __hip_bfloat16* __restrict__ We2t) {
  __shared__ float tile[32][33];
  const int z = blockIdx.z;
  int R, C;
  const float* inb;
  __hip_bfloat16* outb;
  if (z < NK) {
    R = ND; C = NH;
    inb = Wt1 + (size_t)z * ND * NH;
    outb = Wt1t + (size_t)z * ND * NH;
  } else if (z < 2 * NK) {
    R = NH; C = ND;
    inb = Wt2 + (size_t)(z - NK) * NH * ND;
    outb = Wt2t + (size_t)(z - NK) * NH * ND;
  } else if (z == 2 * NK) {
    R = ND; C = NH;
    inb = We1; outb = We1t;
  } else {
    R = NH; C = NH;
    inb = We2; outb = We2t;
  }
  int cx = blockIdx.x * 32 + threadIdx.x;
  int ry = blockIdx.y * 32;
  if (blockIdx.x * 32 >= C || ry >= R) return;  // uniform early-out
  for (int j = threadIdx.y; j < 32; j += 8)
    tile[j][threadIdx.x] = inb[(size_t)(ry + j) * C + cx];
  __syncthreads();
  int ox = ry + threadIdx.x;
  int oy = blockIdx.x * 32;
  for (int j = threadIdx.y; j < 32; j += 8)
    outb[(size_t)(oy + j) * R + ox] = __float2bfloat16(tile[threadIdx.x][j]);
}

__device__ __forceinline__ float fast_tanh(float x) {
  float e = __expf(2.0f * x);
  return 1.0f - 2.0f / (e + 1.0f);
}

// ---------------------------------------------------------------------------
// MFMA GEMM (NT): C[M,N] = act(A[M,Kd] * Bt[N,Kd]^T + bias[N])
// TM x TN block tile, (TM/64)*(TN/64) waves, wave = 64x64 sub-tile via 4x4
// mfma_f32_16x16x32_bf16. Verified ladder: 128/128 MfmaUtil 29 ->
// 256/128 41.5 (R9-R11, 794 us total). R12's all-256x256 crashed (cause
// unisolated: 1024-thr + 64 KB LDS first used together). R13: 256x256 on
// G4 ONLY as the isolation experiment; G1-G3 stay at the R11 config.
// [R7 lesson: do NOT re-attempt direct-B / single-barrier pipelining.]
// Grid x = row panel (XCD affinity: FETCH 198->41MB, R4). XOR chunk
// swizzles (conflict-free R5-R11). MFMA operands swapped -> lane holds 4
// consecutive cols of C -> 8 B packed stores.
// EPI: 1 = tanh->bf16, 2 = relu->bf16, 3 = plain->bf16
// ---------------------------------------------------------------------------
template <int EPI, int BK, int TM, int TN>
__global__ __launch_bounds__((TM / 64) * (TN / 64) * 64) void gemm_bt(
    const __hip_bfloat16* __restrict__ A, long sAz, int lda,
    const __hip_bfloat16* __restrict__ Bt, long sBz, int ldb,
    const float* __restrict__ bias, long sBiasZ,
    __hip_bfloat16* __restrict__ C, long sCz, int ldc, int Kd) {
  __shared__ __align__(16) __hip_bfloat16 As[TM * BK];
  __shared__ __align__(16) __hip_bfloat16 Bs[TN * BK];

  const int z = blockIdx.z;
  const __hip_bfloat16* Ab = A + (size_t)z * sAz;
  const __hip_bfloat16* Bb = Bt + (size_t)z * sBz;
  const float* biasb = bias + (size_t)z * sBiasZ;
  __hip_bfloat16* Cb = C + (size_t)z * sCz;

  const int bm = blockIdx.x, bn = blockIdx.y;  // x = row panel (XCD affinity)
  const int t = threadIdx.x;
  constexpr int NWN = TN / 64;
  constexpr int T = (TM / 64) * NWN * 64;  // threads
  const int lane = t & 63, w = t >> 6;
  const int wm = w / NWN, wn = w % NWN;
  const int r = lane & 15, q = lane >> 4;

  f32x4 acc[4][4] = {};

  // Staging chunk->(row, global-offset) with XOR swizzle (self-inverse).
  auto chunk_row = [&](int c) {
    return (BK == 32) ? (c >> 2) : (c >> 3);
  };
  auto chunk_gofs = [&](int c, int row) {
    return (BK == 32) ? ((((c & 3) ^ ((row >> 1) & 3)) * 8))
                      : ((((c & 7) ^ (row & 7)) * 8));
  };
  constexpr int CPTA = TM * BK / 8 / T;  // A chunks per thread
  constexpr int CPTB = TN * BK / 8 / T;  // B chunks per thread
  const size_t rowA = (size_t)bm * TM, rowB = (size_t)bn * TN;

  for (int k0 = 0; k0 < Kd; k0 += BK) {
#pragma unroll
    for (int m = 0; m < CPTA; ++m) {
      int c = t + m * T;
      int rw = chunk_row(c);
      __builtin_amdgcn_global_load_lds(
          (const __attribute__((address_space(1))) void*)(Ab + (rowA + rw) * lda + k0 + chunk_gofs(c, rw)),
          (__attribute__((address_space(3))) void*)(As + c * 8), 16, 0, 0);
    }
#pragma unroll
    for (int m = 0; m < CPTB; ++m) {
      int c = t + m * T;
      int rw = chunk_row(c);
      __builtin_amdgcn_global_load_lds(
          (const __attribute__((address_space(1))) void*)(Bb + (rowB + rw) * ldb + k0 + chunk_gofs(c, rw)),
          (__attribute__((address_space(3))) void*)(Bs + c * 8), 16, 0, 0);
    }
    __syncthreads();

#pragma unroll
    for (int ks = 0; ks < BK / 32; ++ks) {
      bf16x8 af[4], bfr[4];
#pragma unroll
      for (int mt = 0; mt < 4; ++mt) {
        int tr = wm * 64 + mt * 16 + r;
        int sl;
        if constexpr (BK == 32) sl = q ^ ((tr >> 1) & 3);
        else sl = (ks * 4 + q) ^ (tr & 7);
        af[mt] = *(const bf16x8*)&As[tr * BK + sl * 8];
      }
#pragma unroll
      for (int nt = 0; nt < 4; ++nt) {
        int tr = wn * 64 + nt * 16 + r;
        int sl;
        if constexpr (BK == 32) sl = q ^ ((tr >> 1) & 3);
        else sl = (ks * 4 + q) ^ (tr & 7);
        bfr[nt] = *(const bf16x8*)&Bs[tr * BK + sl * 8];
      }
#pragma unroll
      for (int mt = 0; mt < 4; ++mt)
#pragma unroll
        for (int nt = 0; nt < 4; ++nt)
          acc[mt][nt] = __builtin_amdgcn_mfma_f32_16x16x32_bf16(
              bfr[nt], af[mt], acc[mt][nt], 0, 0, 0);
    }
    __syncthreads();
  }

  // Epilogue (operand-swapped): lane holds M-row = mt*16 + r, N-cols =
  // nt*16 + q*4 + j (consecutive) -> 8 B packed stores.
  const int colg0 = bn * TN + wn * 64;
  const int rowg0 = bm * TM + wm * 64;
#pragma unroll
  for (int mt = 0; mt < 4; ++mt) {
    int row = rowg0 + mt * 16 + r;
#pragma unroll
    for (int nt = 0; nt < 4; ++nt) {
      int col = colg0 + nt * 16 + q * 4;
      const f32x4 bv = *(const f32x4*)&biasb[col];
      union {
        __hip_bfloat16 h[4];
        uint2 u;
      } pk;
#pragma unroll
      for (int j = 0; j < 4; ++j) {
        float v = acc[mt][nt][j] + bv[j];
        if (EPI == 1) v = fast_tanh(v);
        if (EPI == 2) v = fmaxf(v, 0.0f);
        pk.h[j] = __float2bfloat16(v);
      }
      *(uint2*)&Cb[(size_t)row * ldc + col] = pk.u;
    }
  }
}

// ---------------------------------------------------------------------------
// Final: zc laid [Bc][12][NH]; 2 waves per b (half-H each), partial Grams
// summed in LDS. Block = 256 thr = 2 b's.
// ---------------------------------------------------------------------------
__global__ __launch_bounds__(256) void final_gram(
    const __hip_bfloat16* __restrict__ zc, float* __restrict__ out, int Bc) {
  __shared__ float Gs[2][2][16][16];
  const int t = threadIdx.x;
  const int w = t >> 6, lane = t & 63;
  const int bi = w >> 1;
  const int hh = w & 1;
  const int b = blockIdx.x * 2 + bi;
  const int r = lane & 15;
  const int q = lane >> 4;

  const int rs = r < 12 ? r : 11;
  const __hip_bfloat16* base =
      zc + ((size_t)b * 12 + rs) * NH + hh * (NH / 2) + q * 8;

  f32x4 acc = {};
#pragma unroll
  for (int k0 = 0; k0 < NH / 2; k0 += 32) {
    bf16x8 a = {};
    if (r < 12) a = *(const bf16x8*)(base + k0);
    acc = __builtin_amdgcn_mfma_f32_16x16x32_bf16(a, a, acc, 0, 0, 0);
  }

#pragma unroll
  for (int j = 0; j < 4; ++j) Gs[bi][hh][q * 4 + j][r] = acc[j];
  __syncthreads();

  if (hh == 0) {
    float term = 0.0f;
    if (lane >= 1 && lane < 12) {
      const float(*G0)[16] = Gs[bi][0];
      const float(*G1)[16] = Gs[bi][1];
      float nrm[12];
#pragma unroll
      for (int i = 0; i < 12; ++i)
        nrm[i] = fmaxf(sqrtf(G0[i][i] + G1[i][i]), 1e-8f);
      const int k = lane;
      float pos = __expf((G0[0][k] + G1[0][k]) / (nrm[0] * nrm[k]));
      float neg = 0.0f;
#pragma unroll
      for (int l = 1; l < 12; ++l)
        if (l != k) neg += __expf((G0[k][l] + G1[k][l]) / (nrm[k] * nrm[l]));
      term = __logf(pos / (pos + neg));
    }
#pragma unroll
    for (int m = 1; m < 16; m <<= 1) term += __shfl_xor(term, m);
    if (lane == 0) out[b] = -term;
  }
}

// ---------------------------------------------------------------------------
extern "C" void kernel_launch(void* const* d_in, const int* in_sizes, int n_in,
                              void* d_out, int out_size, void* d_ws,
                              size_t ws_size, hipStream_t stream) {
  const float* x = (const float*)d_in[0];    // [B,D]
  const float* Wt1 = (const float*)d_in[1];  // [K,D,H]
  const float* bt1 = (const float*)d_in[2];  // [K,H]
  const float* Wt2 = (const float*)d_in[3];  // [K,H,D]
  const float* bt2 = (const float*)d_in[4];  // [K,D]
  const float* We1 = (const float*)d_in[5];  // [D,H]
  const float* be1 = (const float*)d_in[6];  // [H]
  const float* We2 = (const float*)d_in[7];  // [H,H]
  const float* be2 = (const float*)d_in[8];  // [H]
  float* out = (float*)d_out;                // [B]

  char* ws = (char*)d_ws;
  size_t off = 0;
  auto alloc = [&](size_t bytes) {
    void* p = ws + off;
    off += (bytes + 255) & ~(size_t)255;
    return p;
  };

  // Persistent bf16 weight transposes (~26 MB)
  __hip_bfloat16* Wt1t = (__hip_bfloat16*)alloc((size_t)NK * NH * ND * 2);  // [K,H,D]
  __hip_bfloat16* Wt2t = (__hip_bfloat16*)alloc((size_t)NK * ND * NH * 2);  // [K,D,H]
  __hip_bfloat16* We1t = (__hip_bfloat16*)alloc((size_t)NH * ND * 2);       // [H,D]
  __hip_bfloat16* We2t = (__hip_bfloat16*)alloc((size_t)NH * NH * 2);       // [H,H]
  const size_t wbytes = off;

  // Pick largest batch chunk Bc (ws in [228,253) MB -> Bc=4096).
  // zc ALIASES txc's region (txc dead after G3).
  int Bc = NB;
  while (Bc > 256) {
    size_t need = wbytes + 2 * ((size_t)12 * Bc * NH * 2) + 4096;
    if (need <= ws_size) break;
    Bc >>= 1;
  }
  __hip_bfloat16* region0 = (__hip_bfloat16*)alloc((size_t)12 * Bc * NH * 2);
  __hip_bfloat16* h1 = (__hip_bfloat16*)alloc((size_t)12 * Bc * NH * 2);
  __hip_bfloat16* txc = region0;  // [12, Bc, ND] during G1..G3
  __hip_bfloat16* zc = region0;   // [Bc, 12, NH] during G4..final

  // One-time: all weight transposes in ONE launch
  transpose_all<<<dim3(NH / 32, NH / 32, 2 * NK + 2), dim3(32, 8), 0,
                  stream>>>(Wt1, Wt2, We1, We2, Wt1t, Wt2t, We1t, We2t);

  for (int cs = 0; cs < NB; cs += Bc) {
    // 1) x chunk -> bf16 (slice 0 of txc)
    cvt_f32_bf16<<<(Bc * ND) / 256, 256, 0, stream>>>(
        x + (size_t)cs * ND, txc, Bc * ND);
    // 2) G1: hx_k = tanh(x @ Wt1[k] + bt1) -> h1 slices 0..10
    //    (R11 config: Kd=512, BK64, 256x128, 512 thr)
    gemm_bt<1, 64, 256, 128><<<dim3(Bc / 256, NH / 128, NK), 512, 0,
                               stream>>>(
        txc, 0L, ND, Wt1t, (long)NH * ND, ND, bt1, (long)NH, h1,
        (long)Bc * NH, NH, ND);
    // 3) G2: tx_k = hx_k @ Wt2[k] + bt2 -> txc slices 1..11
    //    (R11 config: Kd=1024, BK64, 256x128)
    gemm_bt<3, 64, 256, 128><<<dim3(Bc / 256, ND / 128, NK), 512, 0,
                               stream>>>(
        h1, (long)Bc * NH, NH, Wt2t, (long)ND * NH, NH, bt2, (long)ND,
        txc + (size_t)Bc * ND, (long)Bc * ND, ND, NH);
    // 4) G3: e1_s = relu(tx_s @ We1 + be1) -> h1 slices 0..11
    //    (R11 config: Kd=512, BK64, 256x128)
    gemm_bt<2, 64, 256, 128><<<dim3(Bc / 256, NH / 128, 12), 512, 0,
                               stream>>>(
        txc, (long)Bc * ND, ND, We1t, 0L, ND, be1, 0L, h1, (long)Bc * NH,
        NH, ND);
    // 5) G4: z_s -> zc [b][s][h] (sCz=NH, ldc=12NH; Kd=1024)
    //    R13 ISOLATION: 256x256 tile, 1024 thr, 64 KB LDS — G4 only.
    gemm_bt<3, 64, 256, 256><<<dim3(Bc / 256, NH / 256, 12), 1024, 0,
                               stream>>>(
        h1, (long)Bc * NH, NH, We2t, 0L, NH, be2, 0L, zc, (long)NH,
        12 * NH, NH);
    // 6) final score
    final_gram<<<Bc / 2, 256, 0, stream>>>(zc, out + cs, Bc);
  }
}